// Round 19
// baseline (277.951 us; speedup 1.0000x reference)
//
#include <hip/hip_runtime.h>
#include <hip/hip_bf16.h>

#define NN 8192
#define CC 384
#define KD 512
#define HWP 1024

typedef __attribute__((ext_vector_type(8))) short bf16x8;
typedef __attribute__((ext_vector_type(4))) float f32x4;

static constexpr float T_OVER_N = 10.0f / 8192.0f;

__device__ __forceinline__ float bf2f(unsigned short u) {
    union { unsigned int i; float f; } x;
    x.i = ((unsigned int)u) << 16;
    return x.f;
}
__device__ __forceinline__ unsigned short f2bf(float f) {
    __hip_bfloat16 h = __float2bfloat16(f);
    unsigned short u;
    __builtin_memcpy(&u, &h, sizeof(u));
    return u;
}

// ---- pipeline fences ----
__device__ __forceinline__ void wait_vm8() {
    asm volatile("s_waitcnt vmcnt(8)" ::: "memory");
    __builtin_amdgcn_sched_barrier(0);
}
__device__ __forceinline__ void wait_vm0() {
    asm volatile("s_waitcnt vmcnt(0)" ::: "memory");
    __builtin_amdgcn_sched_barrier(0);
}
__device__ __forceinline__ void rawbar() {
    __builtin_amdgcn_s_barrier();
    __builtin_amdgcn_sched_barrier(0);
}

// ---------- 128x64 bf16 tile staging via global_load_lds (16B), source-side XOR swizzle ----------
__device__ __forceinline__ void stage_tile(const unsigned short* __restrict__ src, long ld,
                                           int k0, unsigned short* lds) {
    const int t = threadIdx.x;  // blockDim == 256
    #pragma unroll
    for (int i = 0; i < 4; ++i) {
        int slot = i * 256 + t;
        int row = slot >> 3;
        int cl = (slot & 7) ^ (row & 7);
        const unsigned short* g = src + (long)row * ld + k0 + cl * 8;
        __builtin_amdgcn_global_load_lds((const __attribute__((address_space(1))) void*)g,
                                         (__attribute__((address_space(3))) void*)(lds + (size_t)slot * 8),
                                         16, 0, 0);
    }
}

__device__ __forceinline__ bf16x8 read_frag(const unsigned short* lds, int r, int chunk) {
    int byte = (r << 7) + (((chunk ^ r) & 7) << 4) + ((chunk & ~7) << 4);
    return *(const bf16x8*)((const char*)lds + byte);
}

__device__ __forceinline__ void gemm_step(const unsigned short* As, const unsigned short* Bs,
                                          int arl, int brl, int lhi, f32x4 (&acc)[4][4]) {
    #pragma unroll
    for (int ks = 0; ks < 2; ++ks) {
        bf16x8 a[4], b[4];
        #pragma unroll
        for (int m = 0; m < 4; ++m) a[m] = read_frag(As, arl + m * 16, ks * 4 + lhi);
        #pragma unroll
        for (int n = 0; n < 4; ++n) b[n] = read_frag(Bs, brl + n * 16, ks * 4 + lhi);
        #pragma unroll
        for (int m = 0; m < 4; ++m)
            #pragma unroll
            for (int n = 0; n < 4; ++n)
                acc[m][n] = __builtin_amdgcn_mfma_f32_16x16x32_bf16(a[m], b[n], acc[m][n], 0, 0, 0);
    }
}

// ---------------- row-normalize FF -> bf16 FFnb; also zero rowsum ----------------
__global__ __launch_bounds__(128) void k_normalize(const float* __restrict__ FF,
                                                   unsigned short* __restrict__ FFnb,
                                                   float* __restrict__ rowsum) {
    int row = blockIdx.x;
    int tid = threadIdx.x;
    if (tid == 0) rowsum[row] = 0.f;
    const float* src = FF + (size_t)row * CC;
    float v0 = src[tid], v1 = src[tid + 128], v2 = src[tid + 256];
    float s = v0 * v0 + v1 * v1 + v2 * v2;
    #pragma unroll
    for (int off = 32; off > 0; off >>= 1) s += __shfl_down(s, off, 64);
    __shared__ float ls[2];
    if ((tid & 63) == 0) ls[tid >> 6] = s;
    __syncthreads();
    float inv = 1.0f / sqrtf(ls[0] + ls[1]);
    unsigned short* dst = FFnb + (size_t)row * CC;
    dst[tid] = f2bf(v0 * inv);
    dst[tid + 128] = f2bf(v1 * inv);
    dst[tid + 256] = f2bf(v2 * inv);
}

// ---------------- kNN: one wave per (pixel-row, image); BOTH variants fused ----------------
__global__ __launch_bounds__(256) void k_knn(const float* __restrict__ im,
                                             unsigned char* __restrict__ res20,
                                             unsigned char* __restrict__ res10) {
    const int lane = threadIdx.x & 63;
    const int id = blockIdx.x * 4 + (threadIdx.x >> 6);   // 0..8191 = (b, p)
    const int p = id & 1023;
    const int b = id >> 10;
    const float* im0 = im + (size_t)b * 3 * HWP;
    float rf0 = (im0[p] + 1.f) * 0.5f;
    float rf1 = (im0[HWP + p] + 1.f) * 0.5f;
    float rf2 = (im0[2 * HWP + p] + 1.f) * 0.5f;
    const int px = p & 31, py = p >> 5;
    float colord[16];
    float sqs[16];
    #pragma unroll
    for (int e = 0; e < 16; ++e) {
        int q = e * 64 + lane;
        float f0 = (im0[q] + 1.f) * 0.5f - rf0;
        float f1 = (im0[HWP + q] + 1.f) * 0.5f - rf1;
        float f2 = (im0[2 * HWP + q] + 1.f) * 0.5f - rf2;
        colord[e] = f0 * f0 + f1 * f1 + f2 * f2;
        int dx = (q & 31) - px, dy = (q >> 5) - py;
        sqs[e] = (float)(dx * dx + dy * dy);
    }
    #pragma unroll
    for (int v = 0; v < 2; ++v) {
        const float s2 = v ? (0.1f / 31.0f) * (0.1f / 31.0f) : (2.0f / 31.0f) * (2.0f / 31.0f);
        const int kneigh = v ? 10 : 20;
        unsigned int key[16];
        #pragma unroll
        for (int e = 0; e < 16; ++e) {
            int q = e * 64 + lane;
            float d = fmaf(s2, sqs[e], colord[e]);
            unsigned int db = __float_as_uint(d);
            key[e] = (q == p) ? 0xFFFFFFFFu : ((db & 0xFFFFFC00u) | (unsigned int)q);
        }
        unsigned int selmask = 0;
        for (int it = 0; it < kneigh; ++it) {
            unsigned int m = key[0];
            #pragma unroll
            for (int e = 1; e < 16; ++e) m = (key[e] < m) ? key[e] : m;
            #pragma unroll
            for (int off = 1; off < 64; off <<= 1) {
                unsigned int o = __shfl_xor(m, off, 64);
                m = (o < m) ? o : m;
            }
            int q = (int)(m & 1023u);
            if ((q & 63) == lane) {
                int e = q >> 6;
                selmask |= 1u << e;
                key[e] = 0xFFFFFFFFu;
            }
        }
        unsigned char* dst = (v ? res10 : res20) + ((size_t)(b * HWP + p)) * HWP;
        #pragma unroll
        for (int e = 0; e < 16; ++e) dst[e * 64 + lane] = (unsigned char)((selmask >> e) & 1u);
    }
}

// ---------------- A: all 2080 upper-tri tiles (merged off-band + same-band mask path) ----------------
__global__ __launch_bounds__(256, 2) void k_gram(const unsigned short* __restrict__ FFnb,
                                                 const unsigned char* __restrict__ res20,
                                                 const unsigned char* __restrict__ res10,
                                                 unsigned short* __restrict__ A,
                                                 float* __restrict__ rowsum) {
    __shared__ __align__(16) unsigned short Sh[4][8192];
    int s = ((blockIdx.x & 7) * 260) + (blockIdx.x >> 3);
    int ti = 0, rem = s;
    while (rem >= 64 - ti) { rem -= 64 - ti; ++ti; }
    const int tj = ti + rem;
    const int row0 = ti * 128, col0 = tj * 128;
    const int tid = threadIdx.x, l = tid & 63, wid = tid >> 6;
    const int wr = (wid >> 1) * 64, wc = (wid & 1) * 64;
    const int arl = wr + (l & 15), brl = wc + (l & 15), lhi = l >> 4;
    f32x4 z = {0.f, 0.f, 0.f, 0.f};
    f32x4 acc[4][4];
    #pragma unroll
    for (int m = 0; m < 4; ++m)
        #pragma unroll
        for (int n = 0; n < 4; ++n) acc[m][n] = z;

    stage_tile(FFnb + (long)row0 * CC, CC, 0, Sh[0]);
    stage_tile(FFnb + (long)col0 * CC, CC, 0, Sh[1]);
    for (int t = 0; t < 6; ++t) {
        const int cur = t & 1, nxt = cur ^ 1;
        if (t + 1 < 6) {
            stage_tile(FFnb + (long)row0 * CC, CC, (t + 1) * 64, Sh[2 * nxt]);
            stage_tile(FFnb + (long)col0 * CC, CC, (t + 1) * 64, Sh[2 * nxt + 1]);
            wait_vm8();
        } else {
            wait_vm0();
        }
        rawbar();
        gemm_step(Sh[2 * cur], Sh[2 * cur + 1], arl, brl, lhi, acc);
        rawbar();
    }
    const bool offd = (ti != tj);
    const bool sameband = (ti >> 3) == (tj >> 3);
    const long mbase = ((long)(ti >> 3)) << 20;
    float rs[4][4];
    float cs[4] = {0.f, 0.f, 0.f, 0.f};
    #pragma unroll
    for (int m = 0; m < 4; ++m)
        #pragma unroll
        for (int r = 0; r < 4; ++r) rs[m][r] = 0.f;
    char* Mir = (char*)Sh;     // last compute used Sh[2..3]
    #pragma unroll
    for (int m = 0; m < 4; ++m) {
        #pragma unroll
        for (int n = 0; n < 4; ++n) {
            #pragma unroll
            for (int r = 0; r < 4; ++r) {
                int il = wr + m * 16 + lhi * 4 + r;
                int jl = wc + n * 16 + (l & 15);
                int gi = row0 + il, gj = col0 + jl;
                float vv = acc[m][n][r];
                vv = (gi == gj) ? 0.f : fmaxf(vv, 0.f);
                if (sameband) {
                    int li = gi & 1023, lj = gj & 1023;
                    unsigned char mm = (unsigned char)(
                        (res20[mbase + (long)li * HWP + lj] & res20[mbase + (long)lj * HWP + li]) |
                        (res10[mbase + (long)li * HWP + lj] & res10[mbase + (long)lj * HWP + li]));
                    vv += 0.1f * (float)mm;
                }
                unsigned short u = f2bf(vv);
                A[(long)gi * NN + gj] = u;
                rs[m][r] += vv;
                if (offd) {
                    cs[n] += vv;
                    *(unsigned short*)(Mir + jl * 256 + ((il * 2) ^ ((jl & 15) << 4))) = u;
                }
            }
        }
    }
    #pragma unroll
    for (int m = 0; m < 4; ++m)
        #pragma unroll
        for (int r = 0; r < 4; ++r) {
            float p = rs[m][r];
            #pragma unroll
            for (int off = 1; off < 16; off <<= 1) p += __shfl_xor(p, off, 64);
            if ((l & 15) == 0) atomicAdd(&rowsum[row0 + wr + m * 16 + lhi * 4 + r], p);
        }
    if (offd) {
        #pragma unroll
        for (int n = 0; n < 4; ++n) {
            float p = cs[n];
            p += __shfl_xor(p, 16, 64);
            p += __shfl_xor(p, 32, 64);
            if (l < 16) atomicAdd(&rowsum[col0 + wc + n * 16 + l], p);
        }
        __syncthreads();
        #pragma unroll
        for (int p8 = 0; p8 < 8; ++p8) {
            int idx = p8 * 256 + tid;
            int jl = idx >> 4;
            int cl = idx & 15;
            int sl = cl ^ (jl & 15);
            bf16x8 v = *(const bf16x8*)(Mir + jl * 256 + sl * 16);
            *(bf16x8*)(A + (long)(col0 + jl) * NN + row0 + cl * 8) = v;
        }
    }
}

// ---------------- Psi transposes: PaT=(T/N)Psi^T, PsT=PaT*Dv (bf16); Dv inline from rowsum ----------------
__global__ __launch_bounds__(256) void k_psiT(const float* __restrict__ Psi,
                                              const float* __restrict__ rowsum,
                                              unsigned short* __restrict__ PaT,
                                              unsigned short* __restrict__ PsT) {
    __shared__ unsigned short tile[128][72];
    __shared__ float Dvs[64];
    const int j0 = blockIdx.x * 64;
    const int n0 = blockIdx.y * 128;
    const int t = threadIdx.x;
    if (t < 64) Dvs[t] = 1.0f / sqrtf(rowsum[j0 + t] * (1.0f / 8191.0f));
    #pragma unroll
    for (int i = 0; i < 8; ++i) {
        int jl = i * 8 + (t >> 5);
        int c4 = (t & 31) * 4;
        float4 vv = *(const float4*)(Psi + (size_t)(j0 + jl) * KD + n0 + c4);
        tile[c4 + 0][jl] = f2bf(vv.x * T_OVER_N);
        tile[c4 + 1][jl] = f2bf(vv.y * T_OVER_N);
        tile[c4 + 2][jl] = f2bf(vv.z * T_OVER_N);
        tile[c4 + 3][jl] = f2bf(vv.w * T_OVER_N);
    }
    __syncthreads();
    const int nl = t >> 1;
    const int jh = (t & 1) * 32;
    unsigned short pa[32], ps[32];
    #pragma unroll
    for (int jj = 0; jj < 32; ++jj) {
        unsigned short u = tile[nl][jh + jj];
        pa[jj] = u;
        ps[jj] = f2bf(bf2f(u) * Dvs[jh + jj]);
    }
    unsigned short* dpa = PaT + (size_t)(n0 + nl) * NN + j0 + jh;
    unsigned short* dps = PsT + (size_t)(n0 + nl) * NN + j0 + jh;
    #pragma unroll
    for (int c = 0; c < 4; ++c) {
        *(bf16x8*)(dpa + c * 8) = *(const bf16x8*)(pa + c * 8);
        *(bf16x8*)(dps + c * 8) = *(const bf16x8*)(ps + c * 8);
    }
}

// ---------------- Wp[kz][i][n] = bf16(sum_{k in half kz} A[i][k]*PsT[n][k]) ----------------
__global__ __launch_bounds__(256, 2) void k_yt5(const unsigned short* __restrict__ A,
                                                const unsigned short* __restrict__ PsT,
                                                unsigned short* __restrict__ Wpart) {
    __shared__ __align__(16) unsigned short Sh[4][8192];
    int slot = (blockIdx.x & 7) * 64 + (blockIdx.x >> 3);   // 0..511
    const int it = slot >> 3;
    const int sub = slot & 7;
    const int nt = sub & 3, kz = sub >> 2;
    const int row0 = it * 128, col0 = nt * 128;
    const int tid = threadIdx.x, l = tid & 63, wid = tid >> 6;
    const int wr = (wid >> 1) * 64, wc = (wid & 1) * 64;
    const int arl = wr + (l & 15), brl = wc + (l & 15), lhi = l >> 4;
    f32x4 z = {0.f, 0.f, 0.f, 0.f};
    f32x4 acc[4][4];
    #pragma unroll
    for (int m = 0; m < 4; ++m)
        #pragma unroll
        for (int n = 0; n < 4; ++n) acc[m][n] = z;

    const unsigned short* Abase = A + (long)row0 * NN;
    const unsigned short* Bbase = PsT + (long)col0 * NN;
    const int kbeg = kz * 4096;
    stage_tile(Abase, NN, kbeg, Sh[0]);
    stage_tile(Bbase, NN, kbeg, Sh[1]);
    for (int t = 0; t < 64; ++t) {
        const int cur = t & 1, nxt = cur ^ 1;
        if (t + 1 < 64) {
            int k1 = kbeg + (t + 1) * 64;
            stage_tile(Abase, NN, k1, Sh[2 * nxt]);
            stage_tile(Bbase, NN, k1, Sh[2 * nxt + 1]);
            wait_vm8();
        } else {
            wait_vm0();
        }
        rawbar();
        gemm_step(Sh[2 * cur], Sh[2 * cur + 1], arl, brl, lhi, acc);
        rawbar();
    }
    unsigned short* Wp = Wpart + (long)kz * NN * KD;
    #pragma unroll
    for (int m = 0; m < 4; ++m) {
        #pragma unroll
        for (int r = 0; r < 4; ++r) {
            int gi = row0 + wr + m * 16 + lhi * 4 + r;
            #pragma unroll
            for (int n = 0; n < 4; ++n) {
                int gj = col0 + wc + n * 16 + (l & 15);
                Wp[(long)gi * KD + gj] = f2bf(acc[m][n][r]);
            }
        }
    }
}

// ---------------- YT[n][i] = bf16( (Wp0+Wp1) * Dv[i] ), Dv inline (transpose combiner) ----------------
__global__ __launch_bounds__(256) void k_comb(const unsigned short* __restrict__ Wpart,
                                              const float* __restrict__ rowsum,
                                              unsigned short* __restrict__ YT) {
    __shared__ unsigned short t64[64][80];
    const int i0 = blockIdx.x * 64;
    const int n0 = blockIdx.y * 64;
    const int t = threadIdx.x;
    int il = t >> 2, nc = (t & 3) * 16;
    const unsigned short* p0 = Wpart + (long)(i0 + il) * KD + n0 + nc;
    const unsigned short* p1 = p0 + (long)NN * KD;
    bf16x8 a0 = *(const bf16x8*)p0;
    bf16x8 a1 = *(const bf16x8*)(p0 + 8);
    bf16x8 b0 = *(const bf16x8*)p1;
    bf16x8 b1 = *(const bf16x8*)(p1 + 8);
    float dvi = 1.0f / sqrtf(rowsum[i0 + il] * (1.0f / 8191.0f));
    #pragma unroll
    for (int e = 0; e < 8; ++e) {
        t64[nc + e][il]     = f2bf((bf2f((unsigned short)a0[e]) + bf2f((unsigned short)b0[e])) * dvi);
        t64[nc + 8 + e][il] = f2bf((bf2f((unsigned short)a1[e]) + bf2f((unsigned short)b1[e])) * dvi);
    }
    __syncthreads();
    int nl = t >> 2, jc = (t & 3) * 16;
    bf16x8 o0 = *(const bf16x8*)(&t64[nl][jc]);
    bf16x8 o1 = *(const bf16x8*)(&t64[nl][jc + 8]);
    *(bf16x8*)(YT + (long)(n0 + nl) * NN + i0 + jc) = o0;
    *(bf16x8*)(YT + (long)(n0 + nl) * NN + i0 + jc + 8) = o1;
}

// ---------------- R += PaT * YT^T (2-phase pipelined, K-split x16) ----------------
__global__ __launch_bounds__(256, 2) void k_r(const unsigned short* __restrict__ PaT,
                                              const unsigned short* __restrict__ YT,
                                              float* __restrict__ R) {
    static const int t1tab[10] = {0,0,0,0,1,1,1,2,2,3};
    static const int t2tab[10] = {0,1,2,3,1,2,3,2,3,3};
    const int t1 = t1tab[blockIdx.x], t2 = t2tab[blockIdx.x], kz = blockIdx.y;
    __shared__ __align__(16) unsigned short Sh[4][8192];
    const int row0 = t1 * 128, col0 = t2 * 128;
    const int tid = threadIdx.x, l = tid & 63, wid = tid >> 6;
    const int wr = (wid >> 1) * 64, wc = (wid & 1) * 64;
    const int arl = wr + (l & 15), brl = wc + (l & 15), lhi = l >> 4;
    f32x4 z = {0.f, 0.f, 0.f, 0.f};
    f32x4 acc[4][4];
    #pragma unroll
    for (int m = 0; m < 4; ++m)
        #pragma unroll
        for (int n = 0; n < 4; ++n) acc[m][n] = z;

    const int kbeg = kz * 512;
    stage_tile(PaT + (long)row0 * NN, NN, kbeg, Sh[0]);
    stage_tile(YT + (long)col0 * NN, NN, kbeg, Sh[1]);
    for (int t = 0; t < 8; ++t) {
        const int cur = t & 1, nxt = cur ^ 1;
        if (t + 1 < 8) {
            int k1 = kbeg + (t + 1) * 64;
            stage_tile(PaT + (long)row0 * NN, NN, k1, Sh[2 * nxt]);
            stage_tile(YT + (long)col0 * NN, NN, k1, Sh[2 * nxt + 1]);
            wait_vm8();
        } else {
            wait_vm0();
        }
        rawbar();
        gemm_step(Sh[2 * cur], Sh[2 * cur + 1], arl, brl, lhi, acc);
        rawbar();
    }
    #pragma unroll
    for (int m = 0; m < 4; ++m) {
        #pragma unroll
        for (int n = 0; n < 4; ++n) {
            #pragma unroll
            for (int r = 0; r < 4; ++r) {
                int gk1 = row0 + wr + m * 16 + lhi * 4 + r;
                int gk2 = col0 + wc + n * 16 + (l & 15);
                atomicAdd(&R[(long)gk1 * KD + gk2], acc[m][n][r]);
            }
        }
    }
}

// ---------------- trace & triu^2 reduction of R ----------------
__global__ __launch_bounds__(256) void k_tri(const float* __restrict__ R,
                                             float* __restrict__ acc2) {
    float tr = 0.f, rg = 0.f;
    for (int idx = blockIdx.x * 256 + threadIdx.x; idx < KD * KD; idx += 64 * 256) {
        int k1 = idx >> 9, k2 = idx & 511;
        float v = R[idx];
        if (k1 == k2) tr += v;
        else if (k1 < k2) rg += v * v;
    }
    #pragma unroll
    for (int off = 32; off > 0; off >>= 1) {
        tr += __shfl_down(tr, off, 64);
        rg += __shfl_down(rg, off, 64);
    }
    __shared__ float lt[4], lr[4];
    int tid = threadIdx.x;
    if ((tid & 63) == 0) { lt[tid >> 6] = tr; lr[tid >> 6] = rg; }
    __syncthreads();
    if (tid == 0) {
        atomicAdd(&acc2[0], lt[0] + lt[1] + lt[2] + lt[3]);
        atomicAdd(&acc2[1], lr[0] + lr[1] + lr[2] + lr[3]);
    }
}

// ---------------- finalize ----------------
__global__ void k_fin(const float* __restrict__ acc2, float* __restrict__ out) {
    out[0] = -acc2[0];
    out[1] = 0.05f * acc2[1];
}

extern "C" void kernel_launch(void* const* d_in, const int* in_sizes, int n_in,
                              void* d_out, int out_size, void* d_ws, size_t ws_size,
                              hipStream_t stream) {
    const float* FF  = (const float*)d_in[0];
    const float* Psi = (const float*)d_in[1];
    const float* im  = (const float*)d_in[2];
    float* out = (float*)d_out;
    char* ws = (char*)d_ws;
    size_t off = 0;
    auto alloc = [&](size_t bytes) {
        size_t o = off;
        off += (bytes + 255) & ~(size_t)255;
        return o;
    };
    unsigned short* FFnb  = (unsigned short*)(ws + alloc((size_t)NN * CC * 2));
    unsigned char* res20  = (unsigned char*)(ws + alloc((size_t)8 * HWP * HWP));
    unsigned char* res10  = (unsigned char*)(ws + alloc((size_t)8 * HWP * HWP));
    float* rowsum         = (float*)(ws + alloc((size_t)NN * 4));
    unsigned short* PaT   = (unsigned short*)(ws + alloc((size_t)KD * NN * 2));
    unsigned short* PsT   = (unsigned short*)(ws + alloc((size_t)KD * NN * 2));
    unsigned short* Wpart = (unsigned short*)(ws + alloc((size_t)2 * NN * KD * 2));
    unsigned short* YT    = (unsigned short*)(ws + alloc((size_t)KD * NN * 2));
    float* R              = (float*)(ws + alloc((size_t)KD * KD * 4));
    float* acc2           = (float*)(ws + alloc(256));
    unsigned short* A     = (unsigned short*)(ws + alloc((size_t)NN * NN * 2));

    hipMemsetAsync(R, 0, (size_t)KD * KD * 4, stream);
    hipMemsetAsync(acc2, 0, 8, stream);

    k_normalize<<<NN, 128, 0, stream>>>(FF, FFnb, rowsum);
    k_knn<<<2048, 256, 0, stream>>>(im, res20, res10);
    k_gram<<<2080, 256, 0, stream>>>(FFnb, res20, res10, A, rowsum);
    k_psiT<<<dim3(128, 4), 256, 0, stream>>>(Psi, rowsum, PaT, PsT);
    k_yt5<<<512, 256, 0, stream>>>(A, PsT, Wpart);
    k_comb<<<dim3(NN / 64, KD / 64), 256, 0, stream>>>(Wpart, rowsum, YT);
    k_r<<<dim3(10, 16), 256, 0, stream>>>(PaT, YT, R);
    k_tri<<<64, 256, 0, stream>>>(R, acc2);
    k_fin<<<1, 1, 0, stream>>>(acc2, out);
}

// Round 20
// 272.819 us; speedup vs baseline: 1.0188x; 1.0188x over previous
//
#include <hip/hip_runtime.h>
#include <hip/hip_bf16.h>

#define NN 8192
#define CC 384
#define KD 512
#define HWP 1024

typedef __attribute__((ext_vector_type(8))) short bf16x8;
typedef __attribute__((ext_vector_type(4))) float f32x4;

static constexpr float T_OVER_N = 10.0f / 8192.0f;

__device__ __forceinline__ float bf2f(unsigned short u) {
    union { unsigned int i; float f; } x;
    x.i = ((unsigned int)u) << 16;
    return x.f;
}
__device__ __forceinline__ unsigned short f2bf(float f) {
    __hip_bfloat16 h = __float2bfloat16(f);
    unsigned short u;
    __builtin_memcpy(&u, &h, sizeof(u));
    return u;
}

// ---- pipeline fences ----
__device__ __forceinline__ void wait_vm8() {
    asm volatile("s_waitcnt vmcnt(8)" ::: "memory");
    __builtin_amdgcn_sched_barrier(0);
}
__device__ __forceinline__ void wait_vm0() {
    asm volatile("s_waitcnt vmcnt(0)" ::: "memory");
    __builtin_amdgcn_sched_barrier(0);
}
__device__ __forceinline__ void rawbar() {
    __builtin_amdgcn_s_barrier();
    __builtin_amdgcn_sched_barrier(0);
}

// ---------- 128x64 bf16 tile staging via global_load_lds (16B), source-side XOR swizzle ----------
__device__ __forceinline__ void stage_tile(const unsigned short* __restrict__ src, long ld,
                                           int k0, unsigned short* lds) {
    const int t = threadIdx.x;  // blockDim == 256
    #pragma unroll
    for (int i = 0; i < 4; ++i) {
        int slot = i * 256 + t;
        int row = slot >> 3;
        int cl = (slot & 7) ^ (row & 7);
        const unsigned short* g = src + (long)row * ld + k0 + cl * 8;
        __builtin_amdgcn_global_load_lds((const __attribute__((address_space(1))) void*)g,
                                         (__attribute__((address_space(3))) void*)(lds + (size_t)slot * 8),
                                         16, 0, 0);
    }
}

__device__ __forceinline__ bf16x8 read_frag(const unsigned short* lds, int r, int chunk) {
    int byte = (r << 7) + (((chunk ^ r) & 7) << 4) + ((chunk & ~7) << 4);
    return *(const bf16x8*)((const char*)lds + byte);
}

__device__ __forceinline__ void gemm_step(const unsigned short* As, const unsigned short* Bs,
                                          int arl, int brl, int lhi, f32x4 (&acc)[4][4]) {
    #pragma unroll
    for (int ks = 0; ks < 2; ++ks) {
        bf16x8 a[4], b[4];
        #pragma unroll
        for (int m = 0; m < 4; ++m) a[m] = read_frag(As, arl + m * 16, ks * 4 + lhi);
        #pragma unroll
        for (int n = 0; n < 4; ++n) b[n] = read_frag(Bs, brl + n * 16, ks * 4 + lhi);
        #pragma unroll
        for (int m = 0; m < 4; ++m)
            #pragma unroll
            for (int n = 0; n < 4; ++n)
                acc[m][n] = __builtin_amdgcn_mfma_f32_16x16x32_bf16(a[m], b[n], acc[m][n], 0, 0, 0);
    }
}

// ---------------- row-normalize FF -> bf16 FFnb; also zero rowsum ----------------
__global__ __launch_bounds__(128) void k_normalize(const float* __restrict__ FF,
                                                   unsigned short* __restrict__ FFnb,
                                                   float* __restrict__ rowsum) {
    int row = blockIdx.x;
    int tid = threadIdx.x;
    if (tid == 0) rowsum[row] = 0.f;
    const float* src = FF + (size_t)row * CC;
    float v0 = src[tid], v1 = src[tid + 128], v2 = src[tid + 256];
    float s = v0 * v0 + v1 * v1 + v2 * v2;
    #pragma unroll
    for (int off = 32; off > 0; off >>= 1) s += __shfl_down(s, off, 64);
    __shared__ float ls[2];
    if ((tid & 63) == 0) ls[tid >> 6] = s;
    __syncthreads();
    float inv = 1.0f / sqrtf(ls[0] + ls[1]);
    unsigned short* dst = FFnb + (size_t)row * CC;
    dst[tid] = f2bf(v0 * inv);
    dst[tid + 128] = f2bf(v1 * inv);
    dst[tid + 256] = f2bf(v2 * inv);
}

// ---------------- kNN: one wave per (pixel-row, image); BOTH variants fused ----------------
__global__ __launch_bounds__(256) void k_knn(const float* __restrict__ im,
                                             unsigned char* __restrict__ res20,
                                             unsigned char* __restrict__ res10) {
    const int lane = threadIdx.x & 63;
    const int id = blockIdx.x * 4 + (threadIdx.x >> 6);   // 0..8191 = (b, p)
    const int p = id & 1023;
    const int b = id >> 10;
    const float* im0 = im + (size_t)b * 3 * HWP;
    float rf0 = (im0[p] + 1.f) * 0.5f;
    float rf1 = (im0[HWP + p] + 1.f) * 0.5f;
    float rf2 = (im0[2 * HWP + p] + 1.f) * 0.5f;
    const int px = p & 31, py = p >> 5;
    float colord[16];
    float sqs[16];
    #pragma unroll
    for (int e = 0; e < 16; ++e) {
        int q = e * 64 + lane;
        float f0 = (im0[q] + 1.f) * 0.5f - rf0;
        float f1 = (im0[HWP + q] + 1.f) * 0.5f - rf1;
        float f2 = (im0[2 * HWP + q] + 1.f) * 0.5f - rf2;
        colord[e] = f0 * f0 + f1 * f1 + f2 * f2;
        int dx = (q & 31) - px, dy = (q >> 5) - py;
        sqs[e] = (float)(dx * dx + dy * dy);
    }
    #pragma unroll
    for (int v = 0; v < 2; ++v) {
        const float s2 = v ? (0.1f / 31.0f) * (0.1f / 31.0f) : (2.0f / 31.0f) * (2.0f / 31.0f);
        const int kneigh = v ? 10 : 20;
        unsigned int key[16];
        #pragma unroll
        for (int e = 0; e < 16; ++e) {
            int q = e * 64 + lane;
            float d = fmaf(s2, sqs[e], colord[e]);
            unsigned int db = __float_as_uint(d);
            key[e] = (q == p) ? 0xFFFFFFFFu : ((db & 0xFFFFFC00u) | (unsigned int)q);
        }
        unsigned int selmask = 0;
        for (int it = 0; it < kneigh; ++it) {
            unsigned int m = key[0];
            #pragma unroll
            for (int e = 1; e < 16; ++e) m = (key[e] < m) ? key[e] : m;
            #pragma unroll
            for (int off = 1; off < 64; off <<= 1) {
                unsigned int o = __shfl_xor(m, off, 64);
                m = (o < m) ? o : m;
            }
            int q = (int)(m & 1023u);
            if ((q & 63) == lane) {
                int e = q >> 6;
                selmask |= 1u << e;
                key[e] = 0xFFFFFFFFu;
            }
        }
        unsigned char* dst = (v ? res10 : res20) + ((size_t)(b * HWP + p)) * HWP;
        #pragma unroll
        for (int e = 0; e < 16; ++e) dst[e * 64 + lane] = (unsigned char)((selmask >> e) & 1u);
    }
}

// ---------------- A off-band tiles: pure GEMM + relu + dual write + rowsums (no masks) ----------------
__global__ __launch_bounds__(256, 2) void k_gram_off(const unsigned short* __restrict__ FFnb,
                                                     unsigned short* __restrict__ A,
                                                     float* __restrict__ rowsum) {
    __shared__ __align__(16) unsigned short Sh[4][8192];
    int s = ((blockIdx.x & 7) * 260) + (blockIdx.x >> 3);
    int ti = 0, rem = s;
    while (rem >= 64 - ti) { rem -= 64 - ti; ++ti; }
    const int tj = ti + rem;
    if ((ti >> 3) == (tj >> 3)) return;   // same-band handled by k_gram_diag
    const int row0 = ti * 128, col0 = tj * 128;
    const int tid = threadIdx.x, l = tid & 63, wid = tid >> 6;
    const int wr = (wid >> 1) * 64, wc = (wid & 1) * 64;
    const int arl = wr + (l & 15), brl = wc + (l & 15), lhi = l >> 4;
    f32x4 z = {0.f, 0.f, 0.f, 0.f};
    f32x4 acc[4][4];
    #pragma unroll
    for (int m = 0; m < 4; ++m)
        #pragma unroll
        for (int n = 0; n < 4; ++n) acc[m][n] = z;

    stage_tile(FFnb + (long)row0 * CC, CC, 0, Sh[0]);
    stage_tile(FFnb + (long)col0 * CC, CC, 0, Sh[1]);
    for (int t = 0; t < 6; ++t) {
        const int cur = t & 1, nxt = cur ^ 1;
        if (t + 1 < 6) {
            stage_tile(FFnb + (long)row0 * CC, CC, (t + 1) * 64, Sh[2 * nxt]);
            stage_tile(FFnb + (long)col0 * CC, CC, (t + 1) * 64, Sh[2 * nxt + 1]);
            wait_vm8();
        } else {
            wait_vm0();
        }
        rawbar();
        gemm_step(Sh[2 * cur], Sh[2 * cur + 1], arl, brl, lhi, acc);
        rawbar();
    }
    float rs[4][4];
    float cs[4] = {0.f, 0.f, 0.f, 0.f};
    #pragma unroll
    for (int m = 0; m < 4; ++m)
        #pragma unroll
        for (int r = 0; r < 4; ++r) rs[m][r] = 0.f;
    char* Mir = (char*)Sh;     // last compute used Sh[2..3]
    #pragma unroll
    for (int m = 0; m < 4; ++m) {
        #pragma unroll
        for (int n = 0; n < 4; ++n) {
            #pragma unroll
            for (int r = 0; r < 4; ++r) {
                int il = wr + m * 16 + lhi * 4 + r;
                int jl = wc + n * 16 + (l & 15);
                float vv = fmaxf(acc[m][n][r], 0.f);
                unsigned short u = f2bf(vv);
                A[(long)(row0 + il) * NN + col0 + jl] = u;
                rs[m][r] += vv;
                cs[n] += vv;
                *(unsigned short*)(Mir + jl * 256 + ((il * 2) ^ ((jl & 15) << 4))) = u;
            }
        }
    }
    #pragma unroll
    for (int m = 0; m < 4; ++m)
        #pragma unroll
        for (int r = 0; r < 4; ++r) {
            float p = rs[m][r];
            #pragma unroll
            for (int off = 1; off < 16; off <<= 1) p += __shfl_xor(p, off, 64);
            if ((l & 15) == 0) atomicAdd(&rowsum[row0 + wr + m * 16 + lhi * 4 + r], p);
        }
    #pragma unroll
    for (int n = 0; n < 4; ++n) {
        float p = cs[n];
        p += __shfl_xor(p, 16, 64);
        p += __shfl_xor(p, 32, 64);
        if (l < 16) atomicAdd(&rowsum[col0 + wc + n * 16 + l], p);
    }
    __syncthreads();
    #pragma unroll
    for (int p8 = 0; p8 < 8; ++p8) {
        int idx = p8 * 256 + tid;
        int jl = idx >> 4;
        int cl = idx & 15;
        int sl = cl ^ (jl & 15);
        bf16x8 v = *(const bf16x8*)(Mir + jl * 256 + sl * 16);
        *(bf16x8*)(A + (long)(col0 + jl) * NN + row0 + cl * 8) = v;
    }
}

// ---------------- A same-band tiles (288): GEMM + relu + kNN mask + diag-zero ----------------
__global__ __launch_bounds__(256, 2) void k_gram_diag(const unsigned short* __restrict__ FFnb,
                                                      const unsigned char* __restrict__ res20,
                                                      const unsigned char* __restrict__ res10,
                                                      unsigned short* __restrict__ A,
                                                      float* __restrict__ rowsum) {
    __shared__ __align__(16) unsigned short Sh[4][8192];
    int s = ((blockIdx.x & 7) * 36) + (blockIdx.x >> 3);   // 288 = 8*36
    int band = s / 36, p = s % 36;
    int a = 0, rem = p;
    while (rem >= 8 - a) { rem -= 8 - a; ++a; }
    const int ti = band * 8 + a, tj = band * 8 + a + rem;
    const int row0 = ti * 128, col0 = tj * 128;
    const int tid = threadIdx.x, l = tid & 63, wid = tid >> 6;
    const int wr = (wid >> 1) * 64, wc = (wid & 1) * 64;
    const int arl = wr + (l & 15), brl = wc + (l & 15), lhi = l >> 4;
    f32x4 z = {0.f, 0.f, 0.f, 0.f};
    f32x4 acc[4][4];
    #pragma unroll
    for (int m = 0; m < 4; ++m)
        #pragma unroll
        for (int n = 0; n < 4; ++n) acc[m][n] = z;

    stage_tile(FFnb + (long)row0 * CC, CC, 0, Sh[0]);
    stage_tile(FFnb + (long)col0 * CC, CC, 0, Sh[1]);
    for (int t = 0; t < 6; ++t) {
        const int cur = t & 1, nxt = cur ^ 1;
        if (t + 1 < 6) {
            stage_tile(FFnb + (long)row0 * CC, CC, (t + 1) * 64, Sh[2 * nxt]);
            stage_tile(FFnb + (long)col0 * CC, CC, (t + 1) * 64, Sh[2 * nxt + 1]);
            wait_vm8();
        } else {
            wait_vm0();
        }
        rawbar();
        gemm_step(Sh[2 * cur], Sh[2 * cur + 1], arl, brl, lhi, acc);
        rawbar();
    }
    const bool offd = (ti != tj);
    const long mbase = ((long)band) << 20;
    float rs[4][4];
    float cs[4] = {0.f, 0.f, 0.f, 0.f};
    #pragma unroll
    for (int m = 0; m < 4; ++m)
        #pragma unroll
        for (int r = 0; r < 4; ++r) rs[m][r] = 0.f;
    char* Mir = (char*)Sh;
    #pragma unroll
    for (int m = 0; m < 4; ++m) {
        #pragma unroll
        for (int n = 0; n < 4; ++n) {
            #pragma unroll
            for (int r = 0; r < 4; ++r) {
                int il = wr + m * 16 + lhi * 4 + r;
                int jl = wc + n * 16 + (l & 15);
                int gi = row0 + il, gj = col0 + jl;
                float vv = acc[m][n][r];
                vv = (gi == gj) ? 0.f : fmaxf(vv, 0.f);
                int li = gi & 1023, lj = gj & 1023;
                unsigned char mm = (unsigned char)(
                    (res20[mbase + (long)li * HWP + lj] & res20[mbase + (long)lj * HWP + li]) |
                    (res10[mbase + (long)li * HWP + lj] & res10[mbase + (long)lj * HWP + li]));
                vv += 0.1f * (float)mm;
                unsigned short u = f2bf(vv);
                A[(long)gi * NN + gj] = u;
                rs[m][r] += vv;
                if (offd) {
                    cs[n] += vv;
                    *(unsigned short*)(Mir + jl * 256 + ((il * 2) ^ ((jl & 15) << 4))) = u;
                }
            }
        }
    }
    #pragma unroll
    for (int m = 0; m < 4; ++m)
        #pragma unroll
        for (int r = 0; r < 4; ++r) {
            float p2 = rs[m][r];
            #pragma unroll
            for (int off = 1; off < 16; off <<= 1) p2 += __shfl_xor(p2, off, 64);
            if ((l & 15) == 0) atomicAdd(&rowsum[row0 + wr + m * 16 + lhi * 4 + r], p2);
        }
    if (offd) {
        #pragma unroll
        for (int n = 0; n < 4; ++n) {
            float p2 = cs[n];
            p2 += __shfl_xor(p2, 16, 64);
            p2 += __shfl_xor(p2, 32, 64);
            if (l < 16) atomicAdd(&rowsum[col0 + wc + n * 16 + l], p2);
        }
        __syncthreads();
        #pragma unroll
        for (int p8 = 0; p8 < 8; ++p8) {
            int idx = p8 * 256 + tid;
            int jl = idx >> 4;
            int cl = idx & 15;
            int sl = cl ^ (jl & 15);
            bf16x8 v = *(const bf16x8*)(Mir + jl * 256 + sl * 16);
            *(bf16x8*)(A + (long)(col0 + jl) * NN + row0 + cl * 8) = v;
        }
    }
}

// ---------------- Psi transposes: PaT=(T/N)Psi^T, PsT=PaT*Dv (bf16); Dv inline from rowsum ----------------
__global__ __launch_bounds__(256) void k_psiT(const float* __restrict__ Psi,
                                              const float* __restrict__ rowsum,
                                              unsigned short* __restrict__ PaT,
                                              unsigned short* __restrict__ PsT) {
    __shared__ unsigned short tile[128][72];
    __shared__ float Dvs[64];
    const int j0 = blockIdx.x * 64;
    const int n0 = blockIdx.y * 128;
    const int t = threadIdx.x;
    if (t < 64) Dvs[t] = 1.0f / sqrtf(rowsum[j0 + t] * (1.0f / 8191.0f));
    #pragma unroll
    for (int i = 0; i < 8; ++i) {
        int jl = i * 8 + (t >> 5);
        int c4 = (t & 31) * 4;
        float4 vv = *(const float4*)(Psi + (size_t)(j0 + jl) * KD + n0 + c4);
        tile[c4 + 0][jl] = f2bf(vv.x * T_OVER_N);
        tile[c4 + 1][jl] = f2bf(vv.y * T_OVER_N);
        tile[c4 + 2][jl] = f2bf(vv.z * T_OVER_N);
        tile[c4 + 3][jl] = f2bf(vv.w * T_OVER_N);
    }
    __syncthreads();
    const int nl = t >> 1;
    const int jh = (t & 1) * 32;
    unsigned short pa[32], ps[32];
    #pragma unroll
    for (int jj = 0; jj < 32; ++jj) {
        unsigned short u = tile[nl][jh + jj];
        pa[jj] = u;
        ps[jj] = f2bf(bf2f(u) * Dvs[jh + jj]);
    }
    unsigned short* dpa = PaT + (size_t)(n0 + nl) * NN + j0 + jh;
    unsigned short* dps = PsT + (size_t)(n0 + nl) * NN + j0 + jh;
    #pragma unroll
    for (int c = 0; c < 4; ++c) {
        *(bf16x8*)(dpa + c * 8) = *(const bf16x8*)(pa + c * 8);
        *(bf16x8*)(dps + c * 8) = *(const bf16x8*)(ps + c * 8);
    }
}

// ---------------- Wp[kz][i][n] = bf16(sum_{k in half kz} A[i][k]*PsT[n][k]) ----------------
__global__ __launch_bounds__(256, 2) void k_yt5(const unsigned short* __restrict__ A,
                                                const unsigned short* __restrict__ PsT,
                                                unsigned short* __restrict__ Wpart) {
    __shared__ __align__(16) unsigned short Sh[4][8192];
    int slot = (blockIdx.x & 7) * 64 + (blockIdx.x >> 3);   // 0..511
    const int it = slot >> 3;
    const int sub = slot & 7;
    const int nt = sub & 3, kz = sub >> 2;
    const int row0 = it * 128, col0 = nt * 128;
    const int tid = threadIdx.x, l = tid & 63, wid = tid >> 6;
    const int wr = (wid >> 1) * 64, wc = (wid & 1) * 64;
    const int arl = wr + (l & 15), brl = wc + (l & 15), lhi = l >> 4;
    f32x4 z = {0.f, 0.f, 0.f, 0.f};
    f32x4 acc[4][4];
    #pragma unroll
    for (int m = 0; m < 4; ++m)
        #pragma unroll
        for (int n = 0; n < 4; ++n) acc[m][n] = z;

    const unsigned short* Abase = A + (long)row0 * NN;
    const unsigned short* Bbase = PsT + (long)col0 * NN;
    const int kbeg = kz * 4096;
    stage_tile(Abase, NN, kbeg, Sh[0]);
    stage_tile(Bbase, NN, kbeg, Sh[1]);
    for (int t = 0; t < 64; ++t) {
        const int cur = t & 1, nxt = cur ^ 1;
        if (t + 1 < 64) {
            int k1 = kbeg + (t + 1) * 64;
            stage_tile(Abase, NN, k1, Sh[2 * nxt]);
            stage_tile(Bbase, NN, k1, Sh[2 * nxt + 1]);
            wait_vm8();
        } else {
            wait_vm0();
        }
        rawbar();
        gemm_step(Sh[2 * cur], Sh[2 * cur + 1], arl, brl, lhi, acc);
        rawbar();
    }
    unsigned short* Wp = Wpart + (long)kz * NN * KD;
    #pragma unroll
    for (int m = 0; m < 4; ++m) {
        #pragma unroll
        for (int r = 0; r < 4; ++r) {
            int gi = row0 + wr + m * 16 + lhi * 4 + r;
            #pragma unroll
            for (int n = 0; n < 4; ++n) {
                int gj = col0 + wc + n * 16 + (l & 15);
                Wp[(long)gi * KD + gj] = f2bf(acc[m][n][r]);
            }
        }
    }
}

// ---------------- YT[n][i] = bf16( (Wp0+Wp1) * Dv[i] ), Dv inline (transpose combiner) ----------------
__global__ __launch_bounds__(256) void k_comb(const unsigned short* __restrict__ Wpart,
                                              const float* __restrict__ rowsum,
                                              unsigned short* __restrict__ YT) {
    __shared__ unsigned short t64[64][80];
    const int i0 = blockIdx.x * 64;
    const int n0 = blockIdx.y * 64;
    const int t = threadIdx.x;
    int il = t >> 2, nc = (t & 3) * 16;
    const unsigned short* p0 = Wpart + (long)(i0 + il) * KD + n0 + nc;
    const unsigned short* p1 = p0 + (long)NN * KD;
    bf16x8 a0 = *(const bf16x8*)p0;
    bf16x8 a1 = *(const bf16x8*)(p0 + 8);
    bf16x8 b0 = *(const bf16x8*)p1;
    bf16x8 b1 = *(const bf16x8*)(p1 + 8);
    float dvi = 1.0f / sqrtf(rowsum[i0 + il] * (1.0f / 8191.0f));
    #pragma unroll
    for (int e = 0; e < 8; ++e) {
        t64[nc + e][il]     = f2bf((bf2f((unsigned short)a0[e]) + bf2f((unsigned short)b0[e])) * dvi);
        t64[nc + 8 + e][il] = f2bf((bf2f((unsigned short)a1[e]) + bf2f((unsigned short)b1[e])) * dvi);
    }
    __syncthreads();
    int nl = t >> 2, jc = (t & 3) * 16;
    bf16x8 o0 = *(const bf16x8*)(&t64[nl][jc]);
    bf16x8 o1 = *(const bf16x8*)(&t64[nl][jc + 8]);
    *(bf16x8*)(YT + (long)(n0 + nl) * NN + i0 + jc) = o0;
    *(bf16x8*)(YT + (long)(n0 + nl) * NN + i0 + jc + 8) = o1;
}

// ---------------- R += PaT * YT^T (2-phase pipelined, K-split x16) ----------------
__global__ __launch_bounds__(256, 2) void k_r(const unsigned short* __restrict__ PaT,
                                              const unsigned short* __restrict__ YT,
                                              float* __restrict__ R) {
    static const int t1tab[10] = {0,0,0,0,1,1,1,2,2,3};
    static const int t2tab[10] = {0,1,2,3,1,2,3,2,3,3};
    const int t1 = t1tab[blockIdx.x], t2 = t2tab[blockIdx.x], kz = blockIdx.y;
    __shared__ __align__(16) unsigned short Sh[4][8192];
    const int row0 = t1 * 128, col0 = t2 * 128;
    const int tid = threadIdx.x, l = tid & 63, wid = tid >> 6;
    const int wr = (wid >> 1) * 64, wc = (wid & 1) * 64;
    const int arl = wr + (l & 15), brl = wc + (l & 15), lhi = l >> 4;
    f32x4 z = {0.f, 0.f, 0.f, 0.f};
    f32x4 acc[4][4];
    #pragma unroll
    for (int m = 0; m < 4; ++m)
        #pragma unroll
        for (int n = 0; n < 4; ++n) acc[m][n] = z;

    const int kbeg = kz * 512;
    stage_tile(PaT + (long)row0 * NN, NN, kbeg, Sh[0]);
    stage_tile(YT + (long)col0 * NN, NN, kbeg, Sh[1]);
    for (int t = 0; t < 8; ++t) {
        const int cur = t & 1, nxt = cur ^ 1;
        if (t + 1 < 8) {
            int k1 = kbeg + (t + 1) * 64;
            stage_tile(PaT + (long)row0 * NN, NN, k1, Sh[2 * nxt]);
            stage_tile(YT + (long)col0 * NN, NN, k1, Sh[2 * nxt + 1]);
            wait_vm8();
        } else {
            wait_vm0();
        }
        rawbar();
        gemm_step(Sh[2 * cur], Sh[2 * cur + 1], arl, brl, lhi, acc);
        rawbar();
    }
    #pragma unroll
    for (int m = 0; m < 4; ++m) {
        #pragma unroll
        for (int n = 0; n < 4; ++n) {
            #pragma unroll
            for (int r = 0; r < 4; ++r) {
                int gk1 = row0 + wr + m * 16 + lhi * 4 + r;
                int gk2 = col0 + wc + n * 16 + (l & 15);
                atomicAdd(&R[(long)gk1 * KD + gk2], acc[m][n][r]);
            }
        }
    }
}

// ---------------- trace & triu^2 reduction of R ----------------
__global__ __launch_bounds__(256) void k_tri(const float* __restrict__ R,
                                             float* __restrict__ acc2) {
    float tr = 0.f, rg = 0.f;
    for (int idx = blockIdx.x * 256 + threadIdx.x; idx < KD * KD; idx += 64 * 256) {
        int k1 = idx >> 9, k2 = idx & 511;
        float v = R[idx];
        if (k1 == k2) tr += v;
        else if (k1 < k2) rg += v * v;
    }
    #pragma unroll
    for (int off = 32; off > 0; off >>= 1) {
        tr += __shfl_down(tr, off, 64);
        rg += __shfl_down(rg, off, 64);
    }
    __shared__ float lt[4], lr[4];
    int tid = threadIdx.x;
    if ((tid & 63) == 0) { lt[tid >> 6] = tr; lr[tid >> 6] = rg; }
    __syncthreads();
    if (tid == 0) {
        atomicAdd(&acc2[0], lt[0] + lt[1] + lt[2] + lt[3]);
        atomicAdd(&acc2[1], lr[0] + lr[1] + lr[2] + lr[3]);
    }
}

// ---------------- finalize ----------------
__global__ void k_fin(const float* __restrict__ acc2, float* __restrict__ out) {
    out[0] = -acc2[0];
    out[1] = 0.05f * acc2[1];
}

extern "C" void kernel_launch(void* const* d_in, const int* in_sizes, int n_in,
                              void* d_out, int out_size, void* d_ws, size_t ws_size,
                              hipStream_t stream) {
    const float* FF  = (const float*)d_in[0];
    const float* Psi = (const float*)d_in[1];
    const float* im  = (const float*)d_in[2];
    float* out = (float*)d_out;
    char* ws = (char*)d_ws;
    size_t off = 0;
    auto alloc = [&](size_t bytes) {
        size_t o = off;
        off += (bytes + 255) & ~(size_t)255;
        return o;
    };
    unsigned short* FFnb  = (unsigned short*)(ws + alloc((size_t)NN * CC * 2));
    unsigned char* res20  = (unsigned char*)(ws + alloc((size_t)8 * HWP * HWP));
    unsigned char* res10  = (unsigned char*)(ws + alloc((size_t)8 * HWP * HWP));
    float* rowsum         = (float*)(ws + alloc((size_t)NN * 4));
    unsigned short* PaT   = (unsigned short*)(ws + alloc((size_t)KD * NN * 2));
    unsigned short* PsT   = (unsigned short*)(ws + alloc((size_t)KD * NN * 2));
    unsigned short* Wpart = (unsigned short*)(ws + alloc((size_t)2 * NN * KD * 2));
    unsigned short* YT    = (unsigned short*)(ws + alloc((size_t)KD * NN * 2));
    float* R              = (float*)(ws + alloc((size_t)KD * KD * 4));
    float* acc2           = (float*)(ws + alloc(256));
    unsigned short* A     = (unsigned short*)(ws + alloc((size_t)NN * NN * 2));

    hipMemsetAsync(R, 0, (size_t)KD * KD * 4, stream);
    hipMemsetAsync(acc2, 0, 8, stream);

    k_normalize<<<NN, 128, 0, stream>>>(FF, FFnb, rowsum);
    k_knn<<<2048, 256, 0, stream>>>(im, res20, res10);
    k_gram_off<<<2080, 256, 0, stream>>>(FFnb, A, rowsum);
    k_gram_diag<<<288, 256, 0, stream>>>(FFnb, res20, res10, A, rowsum);
    k_psiT<<<dim3(128, 4), 256, 0, stream>>>(Psi, rowsum, PaT, PsT);
    k_yt5<<<512, 256, 0, stream>>>(A, PsT, Wpart);
    k_comb<<<dim3(NN / 64, KD / 64), 256, 0, stream>>>(Wpart, rowsum, YT);
    k_r<<<dim3(10, 16), 256, 0, stream>>>(PaT, YT, R);
    k_tri<<<64, 256, 0, stream>>>(R, acc2);
    k_fin<<<1, 1, 0, stream>>>(acc2, out);
}